// Round 1
// baseline (97.024 us; speedup 1.0000x reference)
//
#include <hip/hip_runtime.h>

// ---------------------------------------------------------------------------
// ConvBlock: y = clip(BN(tr(conv3x3(x^2, Wconv))), -1, 1)
// where Wconv[oc][c][di][dj] = weight[oc>>3][(c*9+3di+dj)>>3][((oc)-(c*9+3di+dj))&7]
// ---------------------------------------------------------------------------

#define A_MORR 0.8578f
#define R_MORR 0.8578f

// tr(phi) = (C1 + C2*cos) / (C3 + C2*cos)
#define TR_C1 (A_MORR * A_MORR + R_MORR * R_MORR)
#define TR_C2 (-2.0f * A_MORR * R_MORR)
#define TR_C3 (1.0f + (A_MORR * R_MORR) * (A_MORR * R_MORR))

#define BN_EPS 1e-5f

// geometry
#define B_  64
#define C_  64
#define HH  32
#define WW  32
#define OC  64
#define KTOT 576           // C_*9
#define NPIX 65536         // B_*HH*WW  (per-channel BN count)

// ws layout (floats)
#define WS_WEXP   0        // [576][64]
#define WS_STATS  36864    // [128]  (sum, sumsq per channel)
#define WS_SS     36992    // [128]  (scale, shift per channel)

// ---------------------------------------------------------------------------
// Kernel A: expand circulant weight into Wexp[k][oc], zero stats
// ---------------------------------------------------------------------------
__global__ __launch_bounds__(256) void prep_kernel(const float* __restrict__ w,
                                                   float* __restrict__ wexp,
                                                   float* __restrict__ stats) {
    int gtid = blockIdx.x * 256 + threadIdx.x;
    if (gtid < 128) stats[gtid] = 0.0f;
    for (int idx = gtid; idx < KTOT * OC; idx += gridDim.x * 256) {
        int k  = idx >> 6;
        int oc = idx & 63;
        // weight[p][q][m]: p = oc>>3 (stride 576), q = k>>3 (stride 8), m = (oc-k)&7
        wexp[idx] = w[(oc >> 3) * 576 + (k >> 3) * 8 + ((oc - k) & 7)];
    }
}

// ---------------------------------------------------------------------------
// Kernel B: fused conv(x^2) + tr + partial BN sums
// grid: (8 row-tiles, 64 batch), block 256
// tile: 4 output rows x 32 cols x 64 oc; thread: 4 px (col ps, rows r0..r0+3) x 8 ch
// ---------------------------------------------------------------------------
__global__ __launch_bounds__(256) void conv_kernel(const float* __restrict__ x,
                                                   const float* __restrict__ wexp,
                                                   float* __restrict__ out,
                                                   float* __restrict__ stats) {
    const int rt  = blockIdx.x;         // row tile 0..7
    const int b   = blockIdx.y;         // batch
    const int r0  = rt * 4;
    const int tid = threadIdx.x;
    const int cg  = tid & 7;            // channel group: oc = cg*8 + u
    const int ps  = tid >> 3;           // pixel slot = output column 0..31

    __shared__ __align__(16) float x2t[16][6][34];   // 3264 floats (c-chunk of 16)
    __shared__ __align__(16) float wt[144][64];      // 9216 floats (k-chunk of 144)

    float acc[4][8];
#pragma unroll
    for (int p = 0; p < 4; ++p)
#pragma unroll
        for (int u = 0; u < 8; ++u) acc[p][u] = 0.0f;

    for (int cc = 0; cc < 4; ++cc) {
        __syncthreads();
        // stage x^2 tile: 16 ch x 6 rows x 34 cols (zero-padded halo)
        for (int idx = tid; idx < 16 * 6 * 34; idx += 256) {
            int cl   = idx / 204;
            int rem  = idx - cl * 204;
            int rr   = rem / 34;
            int cp   = rem - rr * 34;
            int gr   = r0 - 1 + rr;
            int gc   = cp - 1;
            float v  = 0.0f;
            if (gr >= 0 && gr < HH && gc >= 0 && gc < WW) {
                float xv = x[(((b * C_) + (cc * 16 + cl)) * HH + gr) * WW + gc];
                v = xv * xv;
            }
            x2t[cl][rr][cp] = v;
        }
        // stage weight chunk: rows cc*144 .. cc*144+143, 64 cols (float4)
        {
            const float4* src = (const float4*)(wexp + cc * 144 * 64);
            float4* dst = (float4*)(&wt[0][0]);
            for (int idx = tid; idx < 144 * 64 / 4; idx += 256) dst[idx] = src[idx];
        }
        __syncthreads();

#pragma unroll 2
        for (int cl = 0; cl < 16; ++cl) {
            // hoist the 6x3 x^2 window for this channel
            float xv[6][3];
#pragma unroll
            for (int rr = 0; rr < 6; ++rr)
#pragma unroll
                for (int d = 0; d < 3; ++d) xv[rr][d] = x2t[cl][rr][ps + d];

#pragma unroll
            for (int di = 0; di < 3; ++di) {
#pragma unroll
                for (int dj = 0; dj < 3; ++dj) {
                    const int kk = cl * 9 + di * 3 + dj;
                    const float4 w0 = *(const float4*)(&wt[kk][cg * 8]);
                    const float4 w1 = *(const float4*)(&wt[kk][cg * 8 + 4]);
#pragma unroll
                    for (int p = 0; p < 4; ++p) {
                        const float s = xv[p + di][dj];
                        acc[p][0] = fmaf(s, w0.x, acc[p][0]);
                        acc[p][1] = fmaf(s, w0.y, acc[p][1]);
                        acc[p][2] = fmaf(s, w0.z, acc[p][2]);
                        acc[p][3] = fmaf(s, w0.w, acc[p][3]);
                        acc[p][4] = fmaf(s, w1.x, acc[p][4]);
                        acc[p][5] = fmaf(s, w1.y, acc[p][5]);
                        acc[p][6] = fmaf(s, w1.z, acc[p][6]);
                        acc[p][7] = fmaf(s, w1.w, acc[p][7]);
                    }
                }
            }
        }
    }

    // epilogue: tr transform, store, per-channel partial sums
    float ts1[8], ts2[8];
#pragma unroll
    for (int u = 0; u < 8; ++u) { ts1[u] = 0.0f; ts2[u] = 0.0f; }

    const int base = ((b * OC) + cg * 8) * 1024 + r0 * 32 + ps;
#pragma unroll
    for (int u = 0; u < 8; ++u) {
#pragma unroll
        for (int p = 0; p < 4; ++p) {
            float phi = acc[p][u];
            float c   = __cosf(phi);
            float num = fmaf(TR_C2, c, TR_C1);
            float den = fmaf(TR_C2, c, TR_C3);
            float t   = num / den;
            out[base + u * 1024 + p * 32] = t;
            ts1[u] += t;
            ts2[u] += t * t;
        }
    }

    // block-level per-channel reduction (reuse wt storage)
    float* red1 = &wt[0][0];
    float* red2 = red1 + 64 * 33;
    __syncthreads();
#pragma unroll
    for (int u = 0; u < 8; ++u) {
        red1[(cg * 8 + u) * 33 + ps] = ts1[u];
        red2[(cg * 8 + u) * 33 + ps] = ts2[u];
    }
    __syncthreads();
    if (tid < 64) {
        float s1 = 0.0f, s2 = 0.0f;
#pragma unroll 4
        for (int p = 0; p < 32; ++p) {
            s1 += red1[tid * 33 + p];
            s2 += red2[tid * 33 + p];
        }
        atomicAdd(&stats[tid], s1);
        atomicAdd(&stats[64 + tid], s2);
    }
}

// ---------------------------------------------------------------------------
// Kernel C: finalize BN scale/shift
// ---------------------------------------------------------------------------
__global__ __launch_bounds__(64) void stats_kernel(const float* __restrict__ stats,
                                                   const float* __restrict__ gamma,
                                                   const float* __restrict__ beta,
                                                   float* __restrict__ ss) {
    int oc = threadIdx.x;
    if (oc >= OC) return;
    const float invN = 1.0f / (float)NPIX;
    float mean = stats[oc] * invN;
    float var  = stats[64 + oc] * invN - mean * mean;
    float sc   = gamma[oc] * rsqrtf(var + BN_EPS);
    ss[oc]      = sc;
    ss[64 + oc] = beta[oc] - mean * sc;
}

// ---------------------------------------------------------------------------
// Kernel D: in-place normalize + clip (float4)
// ---------------------------------------------------------------------------
__global__ __launch_bounds__(256) void norm_kernel(float* __restrict__ out,
                                                   const float* __restrict__ ss) {
    int i = blockIdx.x * 256 + threadIdx.x;   // float4 index, 1048576 total
    float4 v = ((float4*)out)[i];
    int oc = (i >> 8) & 63;
    float sc = ss[oc];
    float sh = ss[64 + oc];
    v.x = fminf(1.0f, fmaxf(-1.0f, fmaf(v.x, sc, sh)));
    v.y = fminf(1.0f, fmaxf(-1.0f, fmaf(v.y, sc, sh)));
    v.z = fminf(1.0f, fmaxf(-1.0f, fmaf(v.z, sc, sh)));
    v.w = fminf(1.0f, fmaxf(-1.0f, fmaf(v.w, sc, sh)));
    ((float4*)out)[i] = v;
}

// ---------------------------------------------------------------------------
extern "C" void kernel_launch(void* const* d_in, const int* in_sizes, int n_in,
                              void* d_out, int out_size, void* d_ws, size_t ws_size,
                              hipStream_t stream) {
    const float* x     = (const float*)d_in[0];
    const float* w     = (const float*)d_in[1];
    const float* gamma = (const float*)d_in[2];
    const float* beta  = (const float*)d_in[3];
    float* out = (float*)d_out;
    float* ws  = (float*)d_ws;

    float* wexp  = ws + WS_WEXP;
    float* stats = ws + WS_STATS;
    float* ss    = ws + WS_SS;

    hipLaunchKernelGGL(prep_kernel, dim3(64), dim3(256), 0, stream, w, wexp, stats);
    hipLaunchKernelGGL(conv_kernel, dim3(8, 64), dim3(256), 0, stream, x, wexp, out, stats);
    hipLaunchKernelGGL(stats_kernel, dim3(1), dim3(64), 0, stream, stats, gamma, beta, ss);
    hipLaunchKernelGGL(norm_kernel, dim3(4096), dim3(256), 0, stream, out, ss);
}

// Round 2
// 49.878 us; speedup vs baseline: 1.9452x; 1.9452x over previous
//
#include <hip/hip_runtime.h>

// ---------------------------------------------------------------------------
// ConvBlock: y = clip(BN(tr(conv3x3(x^2, Wconv))), -1, 1)
// Wconv[oc][c][di][dj] = weight[oc>>3][(c*9+3di+dj)>>3][(oc-(c*9+3di+dj))&7]
// GEMM form: A = Wconv (M=64 oc), B = im2col(x^2) (N=65536 px), K=576.
// bf16 MFMA 32x32x16, 3-pass hi/lo precision split.
// ---------------------------------------------------------------------------

#define A_MORR 0.8578f
#define R_MORR 0.8578f
#define TR_C1 (A_MORR * A_MORR + R_MORR * R_MORR)
#define TR_C2 (-2.0f * A_MORR * R_MORR)
#define TR_C3 (1.0f + (A_MORR * R_MORR) * (A_MORR * R_MORR))
#define BN_EPS 1e-5f

#define NPIX 65536
#define X2_LO 26112          // byte offset of lo-precision x2 plane in LDS
#define SMEM_BYTES 52224

typedef __attribute__((ext_vector_type(8))) short bf16x8;
typedef __attribute__((ext_vector_type(16))) float f32x16;

__device__ __forceinline__ void bf16split(float s, unsigned short& h, unsigned short& l) {
    union { float f; unsigned u; } cv; cv.f = s;
    unsigned r = (cv.u + 0x7fffu + ((cv.u >> 16) & 1u)) & 0xffff0000u;
    h = (unsigned short)(r >> 16);
    union { unsigned u; float f; } hv; hv.u = r;
    float lo = s - hv.f;
    cv.f = lo;
    unsigned r2 = cv.u + 0x7fffu + ((cv.u >> 16) & 1u);
    l = (unsigned short)(r2 >> 16);
}

// ---------------------------------------------------------------------------
// Kernel A: build fragment-ready bf16 hi/lo weights + zero stats.
// Layout: wfrag[(off*4+ks)*2+mt][prec][lane][8ch] : 72 * 2048 B = 147456 B
//   oc = mt*32 + (lane&31) ; c = ks*16 + (lane>>5)*8 + j ; off = di*3+dj
// ---------------------------------------------------------------------------
__global__ __launch_bounds__(256) void prep_kernel(const float* __restrict__ w,
                                                   char* __restrict__ wfrag,
                                                   float* __restrict__ stats) {
    int gtid = blockIdx.x * 256 + threadIdx.x;
    if (gtid < 128) stats[gtid] = 0.0f;
    if (gtid < 36864) {
        int j    = gtid & 7;
        int lane = (gtid >> 3) & 63;
        int okm  = gtid >> 9;           // ((off*4+ks)*2+mt), 0..71
        int mt   = okm & 1;
        int ks   = (okm >> 1) & 3;
        int off  = okm >> 3;
        int oc   = mt * 32 + (lane & 31);
        int c    = ks * 16 + (lane >> 5) * 8 + j;
        int kg   = c * 9 + off;
        float val = w[(oc >> 3) * 576 + (kg >> 3) * 8 + ((oc - kg) & 7)];
        unsigned short h, l;
        bf16split(val, h, l);
        ((unsigned short*)(wfrag + okm * 2048))[lane * 8 + j] = h;
        ((unsigned short*)(wfrag + okm * 2048 + 1024))[lane * 8 + j] = l;
    }
}

// ---------------------------------------------------------------------------
// Kernel B: MFMA conv + tr + partial BN sums.
// grid (8 row-tiles, 64 batch), block 256 (4 waves).
// Block tile: 64 oc x 128 px (4 image rows). Wave (wmt,py): 32 oc x 64 px.
// LDS x2 tile: [6 rows][34 cols][64 ch] bf16, hi+lo planes, granule-XOR swizzle:
//   byte(prec,r,c,ch) = prec*26112 + ((r*34+c)<<7) + (((ch>>3)^(c&7))<<4) + (ch&7)*2
// ---------------------------------------------------------------------------
__global__ __launch_bounds__(256, 2) void conv_kernel(const float* __restrict__ x,
                                                      const char* __restrict__ wfrag,
                                                      float* __restrict__ out,
                                                      float* __restrict__ stats) {
    const int rt  = blockIdx.x;
    const int b   = blockIdx.y;
    const int tid = threadIdx.x;

    __shared__ __align__(16) char smem[SMEM_BYTES];

    // ---- zero halo cols (c=0 and c=33), all rows/ch/prec: 192 uint4 writes ----
    if (tid < 192) {
        int prec = tid & 1;
        int g    = (tid >> 1) & 7;
        int rc   = tid >> 4;             // 0..11
        int r    = rc >> 1;
        int c    = (rc & 1) ? 33 : 0;
        *(uint4*)(smem + prec * X2_LO + ((r * 34 + c) << 7) + (g << 4)) = uint4{0, 0, 0, 0};
    }

    // ---- stage x^2 (hi/lo) ----
    {
        const int co  = tid & 7;          // col quad: img cols co*4 .. co*4+3
        const int chp = tid >> 3;         // channel pair: ch 2chp, 2chp+1
        const float* xb = x + (size_t)(b * 64 + 2 * chp) * 1024;
#pragma unroll
        for (int rr = 0; rr < 6; ++rr) {
            int gr = rt * 4 - 1 + rr;
            float4 a0 = {0.f, 0.f, 0.f, 0.f}, a1 = {0.f, 0.f, 0.f, 0.f};
            if (gr >= 0 && gr < 32) {
                const float* rp = xb + gr * 32 + co * 4;
                a0 = *(const float4*)rp;
                a1 = *(const float4*)(rp + 1024);
            }
            float s0[4] = {a0.x * a0.x, a0.y * a0.y, a0.z * a0.z, a0.w * a0.w};
            float s1[4] = {a1.x * a1.x, a1.y * a1.y, a1.z * a1.z, a1.w * a1.w};
#pragma unroll
            for (int i = 0; i < 4; ++i) {
                unsigned short h0, l0, h1, l1;
                bf16split(s0[i], h0, l0);
                bf16split(s1[i], h1, l1);
                int c    = 1 + co * 4 + i;
                int base = ((rr * 34 + c) << 7) + ((((2 * chp) >> 3) ^ (c & 7)) << 4)
                         + ((chp & 3) << 2);
                *(unsigned*)(smem + base)         = (unsigned)h0 | ((unsigned)h1 << 16);
                *(unsigned*)(smem + X2_LO + base) = (unsigned)l0 | ((unsigned)l1 << 16);
            }
        }
    }
    __syncthreads();

    // ---- K loop: 9 taps x 4 ksteps, 3-precision MFMA ----
    const int lane = tid & 63;
    const int wv   = tid >> 6;
    const int wmt  = wv & 1;             // oc half
    const int py   = wv >> 1;            // px row pair
    const int col  = lane & 31;
    const int hs   = lane >> 5;

    f32x16 acc0, acc1;
#pragma unroll
    for (int i = 0; i < 16; ++i) { acc0[i] = 0.f; acc1[i] = 0.f; }

#pragma unroll
    for (int di = 0; di < 3; ++di) {
#pragma unroll
        for (int dj = 0; dj < 3; ++dj) {
            const int off = di * 3 + dj;
            const int c   = col + dj;                 // LDS col (img col +1 -1 +dj)
            const int c7  = c & 7;
            const int rc0 = (((py * 2 + di) * 34 + c) << 7);
            const int rc1 = rc0 + (34 << 7);
#pragma unroll
            for (int ks = 0; ks < 4; ++ks) {
                const int gsw = ((ks * 2 + hs) ^ c7) << 4;
                bf16x8 bh0 = *(const bf16x8*)(smem + rc0 + gsw);
                bf16x8 bl0 = *(const bf16x8*)(smem + X2_LO + rc0 + gsw);
                bf16x8 bh1 = *(const bf16x8*)(smem + rc1 + gsw);
                bf16x8 bl1 = *(const bf16x8*)(smem + X2_LO + rc1 + gsw);
                const char* wp = wfrag + ((off * 4 + ks) * 2 + wmt) * 2048 + lane * 16;
                bf16x8 ah = *(const bf16x8*)wp;
                bf16x8 al = *(const bf16x8*)(wp + 1024);
                acc0 = __builtin_amdgcn_mfma_f32_32x32x16_bf16(ah, bh0, acc0, 0, 0, 0);
                acc1 = __builtin_amdgcn_mfma_f32_32x32x16_bf16(ah, bh1, acc1, 0, 0, 0);
                acc0 = __builtin_amdgcn_mfma_f32_32x32x16_bf16(ah, bl0, acc0, 0, 0, 0);
                acc1 = __builtin_amdgcn_mfma_f32_32x32x16_bf16(ah, bl1, acc1, 0, 0, 0);
                acc0 = __builtin_amdgcn_mfma_f32_32x32x16_bf16(al, bh0, acc0, 0, 0, 0);
                acc1 = __builtin_amdgcn_mfma_f32_32x32x16_bf16(al, bh1, acc1, 0, 0, 0);
            }
        }
    }

    // ---- epilogue: tr, store, BN partial sums ----
    float* red1 = (float*)smem;                 // [64][66]
    float* red2 = red1 + 64 * 66;
    float ps1 = 0.f, ps2 = 0.f;
    const int ocr = tid & 63, q = tid >> 6;
    const size_t outbase = ((size_t)b * 64 + wmt * 32) * 1024 + rt * 128;

#pragma unroll
    for (int nt = 0; nt < 2; ++nt) {
        __syncthreads();                         // x2 reads done / red free
        const int pxr = (py * 2 + nt) * 32 + col;
#pragma unroll
        for (int r = 0; r < 16; ++r) {
            int ocl   = (r & 3) + 8 * (r >> 2) + 4 * hs;
            float phi = nt ? acc1[r] : acc0[r];
            float cph = __cosf(phi);
            float t   = fmaf(TR_C2, cph, TR_C1) / fmaf(TR_C2, cph, TR_C3);
            out[outbase + (size_t)ocl * 1024 + pxr] = t;
            int ri = (wmt * 32 + ocl) * 66 + py * 32 + col;
            red1[ri] = t;
            red2[ri] = t * t;
        }
        __syncthreads();
        float s1 = 0.f, s2 = 0.f;
#pragma unroll
        for (int i = 0; i < 16; ++i) {
            s1 += red1[ocr * 66 + q * 16 + i];
            s2 += red2[ocr * 66 + q * 16 + i];
        }
        ps1 += s1; ps2 += s2;
    }
    __syncthreads();
    red1[tid] = ps1;
    red2[tid] = ps2;
    __syncthreads();
    if (tid < 64) {
        float s1 = red1[tid] + red1[tid + 64] + red1[tid + 128] + red1[tid + 192];
        float s2 = red2[tid] + red2[tid + 64] + red2[tid + 128] + red2[tid + 192];
        atomicAdd(&stats[tid], s1);
        atomicAdd(&stats[64 + tid], s2);
    }
}

// ---------------------------------------------------------------------------
// Kernel C: finalize BN scale/shift
// ---------------------------------------------------------------------------
__global__ __launch_bounds__(64) void stats_kernel(const float* __restrict__ stats,
                                                   const float* __restrict__ gamma,
                                                   const float* __restrict__ beta,
                                                   float* __restrict__ ss) {
    int oc = threadIdx.x;
    if (oc >= 64) return;
    const float invN = 1.0f / (float)NPIX;
    float mean = stats[oc] * invN;
    float var  = stats[64 + oc] * invN - mean * mean;
    float sc   = gamma[oc] * rsqrtf(var + BN_EPS);
    ss[oc]      = sc;
    ss[64 + oc] = beta[oc] - mean * sc;
}

// ---------------------------------------------------------------------------
// Kernel D: in-place normalize + clip (float4)
// ---------------------------------------------------------------------------
__global__ __launch_bounds__(256) void norm_kernel(float* __restrict__ out,
                                                   const float* __restrict__ ss) {
    int i = blockIdx.x * 256 + threadIdx.x;
    float4 v = ((float4*)out)[i];
    int oc = (i >> 8) & 63;
    float sc = ss[oc];
    float sh = ss[64 + oc];
    v.x = fminf(1.0f, fmaxf(-1.0f, fmaf(v.x, sc, sh)));
    v.y = fminf(1.0f, fmaxf(-1.0f, fmaf(v.y, sc, sh)));
    v.z = fminf(1.0f, fmaxf(-1.0f, fmaf(v.z, sc, sh)));
    v.w = fminf(1.0f, fmaxf(-1.0f, fmaf(v.w, sc, sh)));
    ((float4*)out)[i] = v;
}

// ---------------------------------------------------------------------------
extern "C" void kernel_launch(void* const* d_in, const int* in_sizes, int n_in,
                              void* d_out, int out_size, void* d_ws, size_t ws_size,
                              hipStream_t stream) {
    const float* x     = (const float*)d_in[0];
    const float* w     = (const float*)d_in[1];
    const float* gamma = (const float*)d_in[2];
    const float* beta  = (const float*)d_in[3];
    float* out = (float*)d_out;

    char*  wfrag = (char*)d_ws;                       // 147456 B
    float* stats = (float*)((char*)d_ws + 147456);    // 128 floats
    float* ss    = stats + 128;                       // 128 floats

    hipLaunchKernelGGL(prep_kernel, dim3(144), dim3(256), 0, stream, w, wfrag, stats);
    hipLaunchKernelGGL(conv_kernel, dim3(8, 64), dim3(256), 0, stream, x, wfrag, out, stats);
    hipLaunchKernelGGL(stats_kernel, dim3(1), dim3(64), 0, stream, stats, gamma, beta, ss);
    hipLaunchKernelGGL(norm_kernel, dim3(4096), dim3(256), 0, stream, out, ss);
}